// Round 6
// baseline (113.946 us; speedup 1.0000x reference)
//
#include <hip/hip_runtime.h>

// Problem shape: E=524288, IN=256, OUT=256, T=16
//   y[t] = x_j[t] @ W[t]       (tiny compute: W is 4 MB total)
//   out[e] = y[edge_types[e]]  (memory-bound gather: 512 MB fp32 writes)
//
// R5 post-mortem: gather ~5.5 TB/s vs fill kernels' 6.7 TB/s. The fill's
// profile: ~3 waves/CU, plain (non-nt) stores, long contiguous runs.
// R6 mimics it: 256 blocks (1/CU) x 4 waves, each wave streams one
// contiguous 512-row (512 KB) span of plain dwordx4 stores; all 512 edge
// types prefetched to LDS in 2 coalesced int4 bursts at span start.

#define RL_IN  256
#define RL_OUT 256
#define RL_T   16

typedef float f32x4 __attribute__((ext_vector_type(4)));

// ---------------------------------------------------------------------------
// Kernel A (fused): y[t][o] = sum_i x[t][i] * W[t][i][o].
// 16 blocks x 1024 threads; thread (c,o) sums 64 i's; LDS reduce over c.
// ---------------------------------------------------------------------------
__global__ __launch_bounds__(1024)
void rl_compute_y(const float* __restrict__ x,
                  const float* __restrict__ W,
                  float* __restrict__ y) {
    const int t = blockIdx.x;            // 0..15
    const int c = threadIdx.x >> 8;      // 0..3
    const int o = threadIdx.x & 255;     // 0..255
    const int i0 = c * 64;

    __shared__ float xs[RL_IN];
    if (threadIdx.x < RL_IN) xs[threadIdx.x] = x[t * RL_IN + threadIdx.x];
    __syncthreads();

    const float* Wt = W + (size_t)t * RL_IN * RL_OUT + (size_t)i0 * RL_OUT;
    float acc = 0.0f;
#pragma unroll 8
    for (int i = 0; i < 64; ++i) {
        acc += xs[i0 + i] * Wt[i * RL_OUT + o];
    }

    __shared__ float part[4][RL_OUT];
    part[c][o] = acc;
    __syncthreads();
    if (c == 0) {
        y[t * RL_OUT + o] = part[0][o] + part[1][o] + part[2][o] + part[3][o];
    }
}

// ---------------------------------------------------------------------------
// Kernel B: gather. 1 block/CU, 4 waves/block. Wave owns a contiguous
// 512-row (512 KB) span: prefetch 512 types (2 KB) in 2 int4 bursts -> LDS,
// then a pure store stream (LDS broadcast read + plain dwordx4 store).
// ---------------------------------------------------------------------------
#define SPAN 512

__global__ __launch_bounds__(256)
void rl_gather(const int* __restrict__ et,    // [E]
               const f32x4* __restrict__ y4,  // [T*64]
               f32x4* __restrict__ out4,      // [E*64]
               int E) {
    __shared__ f32x4 ys[RL_T * (RL_OUT / 4)];  // 1024 * 16B = 16 KB
    __shared__ int tys[4][SPAN];               // 8 KB

    for (int i = threadIdx.x; i < RL_T * (RL_OUT / 4); i += blockDim.x)
        ys[i] = y4[i];

    const int lane = threadIdx.x & 63;
    const int w    = threadIdx.x >> 6;                  // wave in block
    const int gw   = blockIdx.x * 4 + w;                // global wave id
    const int nW   = gridDim.x * 4;

    __syncthreads();  // ys ready

    const int4* et4 = (const int4*)et;

    for (long base = (long)gw * SPAN; base < E; base += (long)nW * SPAN) {
        if (base + SPAN <= E) {
            // prefetch this span's 512 edge types: 2 coalesced 1KB bursts
            int4* t4 = (int4*)tys[w];
            t4[lane]      = et4[base / 4 + lane];
            t4[64 + lane] = et4[base / 4 + 64 + lane];
            // same-wave ds ordering: no barrier needed before reads below
            size_t o0 = (size_t)base * 64 + lane;
#pragma unroll 8
            for (int r = 0; r < SPAN; ++r) {
                const int t = tys[w][r];          // LDS broadcast (uniform)
                out4[o0 + (size_t)r * 64] = ys[t * 64 + lane];
            }
        } else {
            // generic tail: per-row uniform global et read (rarely taken)
            for (long row = base; row < E; ++row) {
                const int t = et[row];
                out4[(size_t)row * 64 + lane] = ys[t * 64 + lane];
            }
        }
    }
}

extern "C" void kernel_launch(void* const* d_in, const int* in_sizes, int n_in,
                              void* d_out, int out_size, void* d_ws, size_t ws_size,
                              hipStream_t stream) {
    const float* x_j  = (const float*)d_in[0];   // [E, IN] (first T rows used)
    const float* W    = (const float*)d_in[1];   // [T, IN, OUT]
    const int*   et   = (const int*)d_in[2];     // [E]
    float*       out  = (float*)d_out;           // [E, OUT]

    const int E = in_sizes[2];                   // 524288

    float* y = (float*)d_ws;                     // [T, OUT] = 16 KB scratch

    rl_compute_y<<<RL_T, 1024, 0, stream>>>(x_j, W, y);

    // 256 blocks (1/CU) x 4 waves x 512 rows = 524288 rows; grid-stride
    // loop keeps it generic for other E.
    rl_gather<<<256, 256, 0, stream>>>(et, (const f32x4*)y,
                                       (f32x4*)out, E);
}